// Round 2
// baseline (104.677 us; speedup 1.0000x reference)
//
#include <hip/hip_runtime.h>
#include <hip/hip_bf16.h>
#include <hip/hip_fp16.h>
#include <math.h>

// B=4096, D=768, K=60. Output: scalar fp32 mean CE loss, label 0.
// loss_b = logsumexp(logits_b) - logits_b[0].
//
// Key change vs 102.9us baseline: the fp16 item table is split into two
// dimension PLANES so each gather pass's working set fits a per-XCD L2:
//   plane A: dims   0..511  -> 4096 x 1024 B = 4.0 MB  (== per-XCD L2)
//   plane B: dims 512..767  -> 4096 x  512 B = 2.0 MB
// Pass A gathers 250 MB against a 4 MB resident set, pass B 125 MB against
// 2 MB, instead of one pass gathering 383 MB against 6.29 MB (L2-thrash).
//
// Phases:
//   1. convert_items_planes: fp32 items -> fp16 planes A/B
//   2. gather_dots_a: one wave per 8 logits; dims 0..511; partial -> ws
//   3. gather_dots_b_lse: one 512-thr block per row; dims 512..767;
//      adds partials, logits in LDS, fused logsumexp -> per-row loss
//   4. final_reduce: one block -> mean into d_out

#define NB 4096
#define ND 768
#define NK 60
#define ND4  (ND / 4)          // 192 float4 per fp32 row
#define NLOGITS (NK + 1)       // 61
#define NPAD 64

// plane A: 256 uints (512 halves) per row; plane B: 128 uints per row
#define PA_ROW_U 256
#define PB_ROW_U 128

#define WS_LOGP_OFF   0                                          // 1 MB partial logits
#define WS_PLANEA_OFF ((size_t)NB * NPAD * 4)                    // +1 MB
#define WS_PLANEB_OFF (WS_PLANEA_OFF + (size_t)NB * PA_ROW_U * 4)// +4 MB
#define WS_LOSS_OFF   (WS_PLANEB_OFF + (size_t)NB * PB_ROW_U * 4)// +2 MB
#define WS_NEED       (WS_LOSS_OFF + (size_t)NB * 4)

typedef _Float16 h2 __attribute__((ext_vector_type(2)));
typedef float    f2 __attribute__((ext_vector_type(2)));

__device__ __forceinline__ float dot2_acc(unsigned int u, unsigned int v, float c) {
#if __has_builtin(__builtin_amdgcn_fdot2)
    return __builtin_amdgcn_fdot2(__builtin_bit_cast(h2, u),
                                  __builtin_bit_cast(h2, v), c, false);
#else
    f2 a = __builtin_convertvector(__builtin_bit_cast(h2, u), f2);
    f2 b = __builtin_convertvector(__builtin_bit_cast(h2, v), f2);
    return c + a.x * b.x + a.y * b.y;
#endif
}

__device__ __forceinline__ unsigned int pack_h2(float x, float y) {
    h2 h = { (_Float16)x, (_Float16)y };
    return __builtin_bit_cast(unsigned int, h);
}

// Butterfly fold: 8 per-lane partials -> every lane holds the full 64-lane
// sum of logit (lane & 7).
__device__ __forceinline__ float fold8(const float acc[8], int lane) {
    const int bit0 = lane & 1;
    float n[4];
    #pragma unroll
    for (int j = 0; j < 4; ++j) {
        float mine  = bit0 ? acc[2*j+1] : acc[2*j];
        float other = bit0 ? acc[2*j]   : acc[2*j+1];
        n[j] = mine + __shfl_xor(other, 1, 64);
    }
    const int bit1 = (lane >> 1) & 1;
    float s[2];
    #pragma unroll
    for (int j = 0; j < 2; ++j) {
        float mine  = bit1 ? s[0] * 0.0f + (bit1 ? n[2*j+1] : n[2*j]) : n[2*j];
        (void)mine;
        float mm = bit1 ? n[2*j+1] : n[2*j];
        float other = bit1 ? n[2*j] : n[2*j+1];
        s[j] = mm + __shfl_xor(other, 2, 64);
    }
    const int bit2 = (lane >> 2) & 1;
    float mine2  = bit2 ? s[1] : s[0];
    float other2 = bit2 ? s[0] : s[1];
    float r = mine2 + __shfl_xor(other2, 4, 64);
    r += __shfl_xor(r, 8, 64);
    r += __shfl_xor(r, 16, 64);
    r += __shfl_xor(r, 32, 64);
    return r;
}

// ---- phase 1: items fp32 -> fp16 planes ----
__global__ __launch_bounds__(256) void convert_items_planes(
    const float4* __restrict__ items,
    unsigned int* __restrict__ planeA,
    unsigned int* __restrict__ planeB)
{
    int i  = blockIdx.x * 256 + threadIdx.x;    // 0 .. NB*ND4-1
    int b  = i / ND4;
    int d4 = i - b * ND4;                       // group of 4 dims
    float4 v = items[i];
    uint2 rv;
    rv.x = pack_h2(v.x, v.y);
    rv.y = pack_h2(v.z, v.w);
    if (d4 < 128)
        ((uint2*)planeA)[(size_t)b * 128 + d4] = rv;
    else
        ((uint2*)planeB)[(size_t)b * 64 + (d4 - 128)] = rv;
}

// ---- phase 2: pass A (dims 0..511); one wave per 8 logits ----
__global__ __launch_bounds__(256, 4) void gather_dots_a(
    const float* __restrict__ user,
    const unsigned int* __restrict__ planeA,
    const int* __restrict__ negidx,
    float* __restrict__ logp)
{
    const int tid  = threadIdx.x;
    const int lane = tid & 63;
    const int w    = blockIdx.x * 4 + (tid >> 6);
    const int b    = w >> 3;
    const int slot = w & 7;

    const int* nrow = negidx + (size_t)b * NK;
    int rows[8];
    #pragma unroll
    for (int i = 0; i < 8; ++i) {
        int k = slot * 8 + i;
        rows[i] = (k == 0 || k > NK) ? b : nrow[k - 1];
    }

    // user dims 0..511 packed to halves: ua.{x,y,z,w} = halves of 8l..8l+7
    const float4* ur4 = (const float4*)(user + (size_t)b * ND);
    float4 uf0 = ur4[2 * lane];
    float4 uf1 = ur4[2 * lane + 1];
    uint4 ua;
    ua.x = pack_h2(uf0.x, uf0.y);
    ua.y = pack_h2(uf0.z, uf0.w);
    ua.z = pack_h2(uf1.x, uf1.y);
    ua.w = pack_h2(uf1.z, uf1.w);

    uint4 va[8];
    #pragma unroll
    for (int i = 0; i < 8; ++i)
        va[i] = ((const uint4*)(planeA + (size_t)rows[i] * PA_ROW_U))[lane];

    float acc[8];
    #pragma unroll
    for (int i = 0; i < 8; ++i) {
        float a = 0.0f;
        a = dot2_acc(ua.x, va[i].x, a);
        a = dot2_acc(ua.y, va[i].y, a);
        a = dot2_acc(ua.z, va[i].z, a);
        a = dot2_acc(ua.w, va[i].w, a);
        acc[i] = a;
    }

    float r = fold8(acc, lane);
    if (lane < 8)
        logp[(size_t)b * NPAD + slot * 8 + lane] = r;
}

// ---- phase 3: pass B (dims 512..767) + fused logsumexp; one block per row ----
__global__ __launch_bounds__(512, 4) void gather_dots_b_lse(
    const float* __restrict__ user,
    const unsigned int* __restrict__ planeB,
    const int* __restrict__ negidx,
    const float* __restrict__ logp,
    float* __restrict__ loss)
{
    const int tid  = threadIdx.x;
    const int lane = tid & 63;
    const int slot = tid >> 6;          // 8 waves = 8 slots
    const int b    = blockIdx.x;

    const int* nrow = negidx + (size_t)b * NK;
    int rows[8];
    #pragma unroll
    for (int i = 0; i < 8; ++i) {
        int k = slot * 8 + i;
        rows[i] = (k == 0 || k > NK) ? b : nrow[k - 1];
    }

    // user dims 512..767: ub.{x,y} = halves of 512+4l..512+4l+3
    const float4* ur4 = (const float4*)(user + (size_t)b * ND);
    float4 uf2 = ur4[128 + lane];
    uint2 ub;
    ub.x = pack_h2(uf2.x, uf2.y);
    ub.y = pack_h2(uf2.z, uf2.w);

    uint2 vb[8];
    #pragma unroll
    for (int i = 0; i < 8; ++i)
        vb[i] = ((const uint2*)(planeB + (size_t)rows[i] * PB_ROW_U))[lane];

    float acc[8];
    #pragma unroll
    for (int i = 0; i < 8; ++i) {
        float a = 0.0f;
        a = dot2_acc(ub.x, vb[i].x, a);
        a = dot2_acc(ub.y, vb[i].y, a);
        acc[i] = a;
    }

    float r = fold8(acc, lane);

    __shared__ float lg[NPAD];
    // add pass-A partial; coalesced 32B read per wave
    float part = logp[(size_t)b * NPAD + slot * 8 + (lane & 7)];
    if (lane < 8)
        lg[slot * 8 + lane] = r + part;
    __syncthreads();

    // wave 0: logsumexp over 61 logits
    if (tid < 64) {
        float v  = (tid < NLOGITS) ? lg[tid] : -INFINITY;
        float p0 = lg[0];
        float m = v;
        #pragma unroll
        for (int off = 32; off > 0; off >>= 1)
            m = fmaxf(m, __shfl_down(m, off, 64));
        m = __shfl(m, 0, 64);
        float e = (tid < NLOGITS) ? __expf(v - m) : 0.0f;
        #pragma unroll
        for (int off = 32; off > 0; off >>= 1)
            e += __shfl_down(e, off, 64);
        if (tid == 0)
            loss[b] = m + __logf(e) - p0;
    }
}

// ---- phase 4: single block reduces 4096 losses -> mean ----
__global__ __launch_bounds__(256) void final_reduce(
    const float* __restrict__ loss, float* __restrict__ out)
{
    const int tid = threadIdx.x;
    const float4* l4 = (const float4*)loss;   // 1024 float4
    float s = 0.0f;
    #pragma unroll
    for (int j = 0; j < 4; ++j) {
        float4 v = l4[tid + 256 * j];
        s += v.x + v.y + v.z + v.w;
    }
    #pragma unroll
    for (int off = 32; off > 0; off >>= 1)
        s += __shfl_down(s, off, 64);
    __shared__ float ps[4];
    if ((tid & 63) == 0) ps[tid >> 6] = s;
    __syncthreads();
    if (tid == 0)
        out[0] = (ps[0] + ps[1] + ps[2] + ps[3]) * (1.0f / (float)NB);
}

// ---- fallback (fp32 single-kernel path) if ws too small ----
__global__ __launch_bounds__(256) void u2i_loss_f32(
    const float* __restrict__ user,
    const float* __restrict__ items,
    const int* __restrict__ negidx,
    float* __restrict__ out)
{
    const int b    = blockIdx.x;
    const int tid  = threadIdx.x;
    const int wave = tid >> 6;
    const int lane = tid & 63;

    __shared__ int   rows_s[NPAD];
    __shared__ float logits[NPAD];

    if (tid < NPAD) {
        const int* nrow = negidx + (size_t)b * NK;
        rows_s[tid] = (tid == 0 || tid > NK) ? b : nrow[tid - 1];
    }
    const float4* u4 = (const float4*)user + (size_t)b * ND4;
    float4 u0 = u4[lane];
    float4 u1 = u4[64 + lane];
    float4 u2 = u4[128 + lane];
    __syncthreads();

    const float4* it4 = (const float4*)items;
    #pragma unroll
    for (int j = 0; j < 4; ++j) {
        int ks[4];
        const float4* p[4];
        #pragma unroll
        for (int i = 0; i < 4; ++i) {
            ks[i] = wave + j * 16 + i * 4;
            p[i]  = it4 + (size_t)rows_s[ks[i]] * ND4;
        }
        float4 v0[4], v1[4], v2[4];
        #pragma unroll
        for (int i = 0; i < 4; ++i) {
            v0[i] = p[i][lane];
            v1[i] = p[i][64 + lane];
            v2[i] = p[i][128 + lane];
        }
        float acc[4];
        #pragma unroll
        for (int i = 0; i < 4; ++i) {
            float a;
            a  = u0.x * v0[i].x + u0.y * v0[i].y + u0.z * v0[i].z + u0.w * v0[i].w;
            a += u1.x * v1[i].x + u1.y * v1[i].y + u1.z * v1[i].z + u1.w * v1[i].w;
            a += u2.x * v2[i].x + u2.y * v2[i].y + u2.z * v2[i].z + u2.w * v2[i].w;
            acc[i] = a;
        }
        #pragma unroll
        for (int off = 32; off > 0; off >>= 1) {
            #pragma unroll
            for (int i = 0; i < 4; ++i)
                acc[i] += __shfl_down(acc[i], off, 64);
        }
        if (lane == 0) {
            #pragma unroll
            for (int i = 0; i < 4; ++i)
                logits[ks[i]] = acc[i];
        }
    }
    __syncthreads();

    if (tid < 64) {
        float v = (tid < NLOGITS) ? logits[tid] : -INFINITY;
        float m = v;
        #pragma unroll
        for (int off = 32; off > 0; off >>= 1)
            m = fmaxf(m, __shfl_down(m, off, 64));
        m = __shfl(m, 0, 64);
        float e = (tid < NLOGITS) ? __expf(v - m) : 0.0f;
        #pragma unroll
        for (int off = 32; off > 0; off >>= 1)
            e += __shfl_down(e, off, 64);
        if (tid == 0) {
            float loss = m + __logf(e) - logits[0];
            atomicAdd(out, loss * (1.0f / (float)NB));
        }
    }
}

extern "C" void kernel_launch(void* const* d_in, const int* in_sizes, int n_in,
                              void* d_out, int out_size, void* d_ws, size_t ws_size,
                              hipStream_t stream) {
    const float* user  = (const float*)d_in[0];   // (B, D) fp32
    const float* items = (const float*)d_in[1];   // (B, D) fp32
    const int*   negi  = (const int*)d_in[2];     // (B, K) int32
    float* out = (float*)d_out;                   // scalar fp32

    if (ws_size >= WS_NEED) {
        char* ws = (char*)d_ws;
        float*        logp   = (float*)(ws + WS_LOGP_OFF);
        unsigned int* planeA = (unsigned int*)(ws + WS_PLANEA_OFF);
        unsigned int* planeB = (unsigned int*)(ws + WS_PLANEB_OFF);
        float*        loss   = (float*)(ws + WS_LOSS_OFF);

        // 786432 float4 -> 3072 blocks of 256
        convert_items_planes<<<(NB * ND / 4) / 256, 256, 0, stream>>>(
            (const float4*)items, planeA, planeB);
        // 4096 rows x 8 waves = 32768 waves = 8192 blocks of 4 waves
        gather_dots_a<<<NB * 8 / 4, 256, 0, stream>>>(
            user, planeA, negi, logp);
        // one 8-wave block per row; fused LSE
        gather_dots_b_lse<<<NB, 512, 0, stream>>>(
            user, planeB, negi, logp, loss);
        final_reduce<<<1, 256, 0, stream>>>(loss, out);
    } else {
        hipMemsetAsync(out, 0, sizeof(float), stream);
        u2i_loss_f32<<<NB, 256, 0, stream>>>(user, items, negi, out);
    }
}